// Round 6
// baseline (130.354 us; speedup 1.0000x reference)
//
#include <hip/hip_runtime.h>
#include <hip/hip_bf16.h>

// Problem constants (match reference)
#define CIN_  128
#define H_    28
#define W_    28
#define COUT_ 32
#define B_    512
// GEMM view per (b,h): Y[32 x 28] = Wm[32 x 384] * Xwin[384 x 28]
// K order: kappa = tap*128 + channel, chunked in 12 chunks of 32.

typedef __attribute__((ext_vector_type(8))) short short8;  // 8 bf16 in 4 VGPRs
typedef __attribute__((ext_vector_type(4))) float f32x4;

__device__ __forceinline__ short f2bf(float f) {
    __hip_bfloat16 h = __float2bfloat16(f);    // RNE, single HW cvt
    union { __hip_bfloat16 h; short s; } u; u.h = h;
    return u.s;
}

// ---------------------------------------------------------------------------
// Pre-pass: build bf16 A-fragments of Wm in d_ws (same layout as before).
// Fragment f = mt*12 + kc; element (lane l, slot j):
//   Wm[jo = mt*16 + (l&15)][i = (kc&3)*32 + (l>>4)*8 + j][tap = kc>>2]
// ---------------------------------------------------------------------------
__global__ void prep_w_kernel(const float* __restrict__ w, short* __restrict__ wsA) {
    int t = blockIdx.x * 256 + threadIdx.x;      // 24*512 = 12288 threads
    int frag = t >> 9;
    int rem  = t & 511;
    int l = rem >> 3;
    int j = rem & 7;
    int mt = frag / 12;
    int kc = frag % 12;
    int tap = kc >> 2;
    int i  = (kc & 3) * 32 + (l >> 4) * 8 + j;
    int jo = mt * 16 + (l & 15);
    wsA[t] = f2bf(w[(jo * CIN_ + i) * 3 + tap]);
}

// ---------------------------------------------------------------------------
// Main kernel v6: persistent 2-tile blocks with cross-barrier prefetch.
// grid 1792 blocks x 256 threads (4 waves); block k handles logical tiles
// T0 = ((k&7)*224 + (k>>3))*2 and T0+1  (XCD-bijective: each XCD gets a
// contiguous range of 448 tiles = 64 batches). Tile T: b = T/7, hg = T%7,
// rows h0..h0+3, wave wv computes row h0+wv.
// Pipeline per block:
//   load vb <- tile0
//   t=0: cvt+ds_write(t0); ISSUE loads(t1);  lgkmcnt(0); s_barrier (raw - no
//        vmcnt drain, prefetch stays in flight);  GEMM(t0); stores(t0);
//        s_barrier
//   t=1: cvt+ds_write(t1) (compiler waits vmcnt); lgkmcnt(0); s_barrier;
//        GEMM(t1); stores(t1)
// LDS per wave-row: [wt 0..29][128 ch] bf16 XOR-swizzled:
//   (wt, i) at short index  wt*128 + (((i>>3) ^ (wt&15))<<3 | (i&7))
// Rows 0 and 29 zeroed once (never overwritten by staging). B-reads with
// wt in 30..33 feed discarded cols (wcol >= 28); clamp row to 29.
// GEMM is mt-outer (6 A-frags live = 24 VGPR) to keep peak VGPR <= 128 while
// the 56-VGPR prefetch is in flight.
// ---------------------------------------------------------------------------
template<bool USE_WS>
__global__ __launch_bounds__(256, 4)
void conv_kernel(const float* __restrict__ x, const float* __restrict__ w,
                 const short* __restrict__ wsA, float* __restrict__ out) {
    __shared__ short lds[4][30 * CIN_];          // 30720 B
    const int tid = threadIdx.x;
    const int wv  = tid >> 6;
    const int l   = tid & 63;

    const int k  = blockIdx.x;                   // 0..1791
    const int T0 = ((k & 7) * 224 + (k >> 3)) * 2;

    // ---- issue tile-0 loads ASAP ----
    f32x4 vb[14];
    {
        const int bb = T0 / 7, hh = T0 % 7;
        const float* xb = x + (size_t)bb * (CIN_ * H_ * W_) + hh * (4 * W_);
#pragma unroll
        for (int it = 0; it < 14; ++it) {
            int f4 = it * 256 + tid;
            int i  = f4 / 28;
            int q  = f4 % 28;
            vb[it] = *reinterpret_cast<const f32x4*>(xb + i * (H_ * W_) + q * 4);
        }
    }

    // ---- zero pad rows wt=0 and wt=29 in this wave's buffer (once) ----
    {
        int s   = (tid & 63) * 4;                // 0..252
        int row = (s >= 128) ? 29 : 0;
        int c   = s & 127;
        *reinterpret_cast<ulong1*>(&lds[wv][row * CIN_ + c]) = ulong1{0};
    }

#pragma unroll
    for (int t = 0; t < 2; ++t) {
        const int T  = T0 + t;
        const int bt = T / 7;
        const int h0 = (T % 7) * 4;

        // ---- cvt + scatter vb -> LDS (consumes vb) ----
#pragma unroll
        for (int it = 0; it < 14; ++it) {
            int f4 = it * 256 + tid;
            int i  = f4 / 28;
            int q  = f4 % 28;
            int hl = q / 7;
            int w4 = q % 7;
            short* buf = lds[hl];
#pragma unroll
            for (int e = 0; e < 4; ++e) {
                int wt   = w4 * 4 + e + 1;       // 1..28
                int sidx = wt * CIN_ + ((((i >> 3) ^ (wt & 15)) << 3) | (i & 7));
                buf[sidx] = f2bf(vb[it][e]);
            }
        }

        // ---- prefetch next tile's loads (stay in flight across barrier) ----
        if (t == 0) {
            const int Tn = T0 + 1;
            const int bb = Tn / 7, hh = Tn % 7;
            const float* xb = x + (size_t)bb * (CIN_ * H_ * W_) + hh * (4 * W_);
#pragma unroll
            for (int it = 0; it < 14; ++it) {
                int f4 = it * 256 + tid;
                int i  = f4 / 28;
                int q  = f4 % 28;
                vb[it] = *reinterpret_cast<const f32x4*>(xb + i * (H_ * W_) + q * 4);
            }
            __builtin_amdgcn_sched_barrier(0);   // pin issue above the barrier
        }

        // ---- barrier 1: ds_writes visible to all waves; NO vmcnt drain ----
        asm volatile("s_waitcnt lgkmcnt(0)" ::: "memory");
        __builtin_amdgcn_sched_barrier(0);
        __builtin_amdgcn_s_barrier();
        __builtin_amdgcn_sched_barrier(0);

        // ---- per-wave GEMM (mt-outer, 6 A-frags live) ----
        f32x4 acc[2][2];
#pragma unroll
        for (int mt = 0; mt < 2; ++mt)
#pragma unroll
            for (int nt = 0; nt < 2; ++nt)
#pragma unroll
                for (int q = 0; q < 4; ++q) acc[mt][nt][q] = 0.0f;

        short* wbuf = lds[wv];
#pragma unroll
        for (int half = 0; half < 2; ++half) {
#pragma unroll
            for (int mt = 0; mt < 2; ++mt) {
                short8 a6[6];
                if (USE_WS) {
#pragma unroll
                    for (int k6 = 0; k6 < 6; ++k6)
                        a6[k6] = *reinterpret_cast<const short8*>(
                            wsA + (mt * 12 + half * 6 + k6) * 512 + l * 8);
                } else {
#pragma unroll
                    for (int k6 = 0; k6 < 6; ++k6) {
                        int kc  = half * 6 + k6;
                        int tap = kc >> 2;
                        int ib  = (kc & 3) * 32 + (l >> 4) * 8;
#pragma unroll
                        for (int j = 0; j < 8; ++j)
                            a6[k6][j] = f2bf(w[((mt * 16 + (l & 15)) * CIN_ + ib + j) * 3 + tap]);
                    }
                }
#pragma unroll
                for (int k6 = 0; k6 < 6; ++k6) {
                    int kc  = half * 6 + k6;
                    int tap = kc >> 2;
                    int c   = (kc & 3) * 4 + (l >> 4);
#pragma unroll
                    for (int nt = 0; nt < 2; ++nt) {
                        int wt  = nt * 16 + (l & 15) + tap;   // 0..33
                        int wtc = wt > 29 ? 29 : wt;          // rows >29 feed dead cols
                        const short8 bfrag = *reinterpret_cast<const short8*>(
                            &wbuf[wtc * CIN_ + ((c ^ (wtc & 15)) << 3)]);
                        acc[mt][nt] = __builtin_amdgcn_mfma_f32_16x16x32_bf16(
                            a6[k6], bfrag, acc[mt][nt], 0, 0, 0);
                    }
                }
            }
        }

        // ---- store with roll: y row h -> out row (h+1)%28 ----
        {
            float* ob = out + (size_t)bt * (COUT_ * H_ * W_);
            const int h  = h0 + wv;
            const int ho = (h + 1 == H_) ? 0 : (h + 1);
#pragma unroll
            for (int mt = 0; mt < 2; ++mt)
#pragma unroll
                for (int nt = 0; nt < 2; ++nt)
#pragma unroll
                    for (int rr = 0; rr < 4; ++rr) {
                        int j    = mt * 16 + (l >> 4) * 4 + rr;
                        int wcol = nt * 16 + (l & 15);
                        if (wcol < W_)
                            ob[(j * H_ + ho) * W_ + wcol] = acc[mt][nt][rr];
                    }
        }

        // ---- barrier 2: all waves done reading LDS before next staging ----
        if (t == 0) {
            __builtin_amdgcn_sched_barrier(0);
            __builtin_amdgcn_s_barrier();        // ds_reads retired via MFMA->store deps
            __builtin_amdgcn_sched_barrier(0);
        }
    }
}

extern "C" void kernel_launch(void* const* d_in, const int* in_sizes, int n_in,
                              void* d_out, int out_size, void* d_ws, size_t ws_size,
                              hipStream_t stream) {
    (void)in_sizes; (void)n_in; (void)out_size;
    const float* x = (const float*)d_in[0];
    const float* w = (const float*)d_in[1];
    float* out = (float*)d_out;

    if (ws_size >= (size_t)(24 * 512 * sizeof(short))) {
        short* wsA = (short*)d_ws;
        prep_w_kernel<<<dim3(48), dim3(256), 0, stream>>>(w, wsA);
        conv_kernel<true><<<dim3(1792), dim3(256), 0, stream>>>(x, w, wsA, out);
    } else {
        conv_kernel<false><<<dim3(1792), dim3(256), 0, stream>>>(x, w, (const short*)nullptr, out);
    }
}